// Round 5
// baseline (171.006 us; speedup 1.0000x reference)
//
#include <hip/hip_runtime.h>
#include <hip/hip_fp16.h>

#define IN_F   4096
#define OUT_F  8192
#define M_ROWS 256

// R5: register-direct GEMM (no LDS, no barriers) with COALESCED B.
// R4 proved the in-register B-dequant fragment mapping correct but died on
// uncoalesced per-lane B loads (4KB lane stride -> latency-bound, 90us).
// Fix: one-shot repack of wq(32MB)+norms(4MB) into a 16MB fragment-ordered
// stream; each lane's per-kstep B record (8 q-bytes + 4 fp16 norms) is one
// dwordx4. A comes from the fragment-ordered bf16 workspace (R4-verified).
// BM=128 via 8-wave blocks (halves R4's dequant replication).
#define SPLITK  4
#define KSTEPS  (IN_F / 32)        // 128 ksteps of K=32 total
#define NIT     (KSTEPS / SPLITK)  // 32 ksteps per block
#define NSTRIPS (OUT_F / 64)       // 128 n-strips of 64

typedef __attribute__((ext_vector_type(8))) short  short8;   // 8 bf16
typedef __attribute__((ext_vector_type(4))) float  float4v;  // 4 fp32 acc

union pk8 { uint4 u; short8 s; };
union hbits { __half h; unsigned short u; };

// pack two fp32 into bf16x2 (truncation): [bf16(lo) | bf16(hi)<<16]
__device__ inline unsigned int pack_bf16(float lo, float hi) {
    return __builtin_amdgcn_perm(__float_as_uint(hi), __float_as_uint(lo), 0x07060302u);
}

__device__ inline float h2f_bits(unsigned int b) {
    hbits t; t.u = (unsigned short)b;
    return __half2float(t.h);
}

// x fp32 -> bf16 workspace in FRAGMENT order (R4-verified): for (kstep ks,
// m-frag mf), 64 lanes x 16B; lane (quad,l15) holds
// x[m = mf*16 + l15][k = ks*32 + quad*8 .. +7].
__global__ void cvt_x_kernel(const float* __restrict__ x, uint4* __restrict__ xb) {
    const int tid = blockIdx.x * blockDim.x + threadIdx.x;
    if (tid >= (M_ROWS * IN_F) / 8) return;
    const int lane = tid & 63;
    const int mf   = (tid >> 6) & 15;
    const int ks   = tid >> 10;
    const int m    = mf * 16 + (lane & 15);
    const int k    = ks * 32 + (lane >> 4) * 8;
    const float* p = x + m * IN_F + k;
    float4 v0 = ((const float4*)p)[0], v1 = ((const float4*)p)[1];
    uint4 o;
    o.x = pack_bf16(v0.x, v0.y); o.y = pack_bf16(v0.z, v0.w);
    o.z = pack_bf16(v1.x, v1.y); o.w = pack_bf16(v1.z, v1.w);
    xb[tid] = o;
}

// out[m][n] = bias[n]  (split-K partials atomicAdd on top)
__global__ void init_out_kernel(const float* __restrict__ bias, float* __restrict__ out) {
    int i = blockIdx.x * blockDim.x + threadIdx.x;
    if (i < (M_ROWS * OUT_F) / 4) {
        float4 b = ((const float4*)bias)[i & (OUT_F / 4 - 1)];
        ((float4*)out)[i] = b;
    }
}

// Repack wq + norms into the fragment-ordered B stream.
// Record r = (strip*KSTEPS + ks)*64 + lane, 16B:
//   ushort[j]   = two q-bytes (weights k0..k0+7) for frag j
//   ushort[4+j] = fp16 norm bits of group covering those 8 k
// where lane=(quad<<4)|l15, n = strip*64 + j*16 + l15, k0 = ks*32 + quad*8.
// Thread <-> (n, ks): reads fully coalesced (32B contiguous per thread).
__global__ void repack_w_kernel(const int* __restrict__ wq,
                                const void* __restrict__ wnorm,
                                unsigned short* __restrict__ bs) {
    const int tid = blockIdx.x * blockDim.x + threadIdx.x;
    if (tid >= OUT_F * KSTEPS) return;
    const int n  = tid >> 7;     // 0..8191
    const int ks = tid & 127;

    // norm storage detection (valid norms in [1e-4,0.0501]; fp16-pair as f32
    // is ~1e-13). Grid-uniform.
    const float cand0 = *(const float*)wnorm;
    const bool  nf32  = (cand0 > 1e-5f && cand0 < 0.1f);

    const int4* wp = (const int4*)(wq + n * (IN_F / 4) + ks * 8);
    int4 w0 = wp[0], w1 = wp[1];

    unsigned short h0, h1;
    const int g = n * (IN_F / 16) + ks * 2;
    if (nf32) {
        const float* nf = (const float*)wnorm;
        hbits a, b; a.h = __float2half(nf[g]); b.h = __float2half(nf[g + 1]);
        h0 = a.u; h1 = b.u;
    } else {
        const unsigned short* nh = (const unsigned short*)wnorm;
        h0 = nh[g]; h1 = nh[g + 1];
    }

    const int b8[8] = { w0.x & 255, w0.y & 255, w0.z & 255, w0.w & 255,
                        w1.x & 255, w1.y & 255, w1.z & 255, w1.w & 255 };
    const int strip = n >> 6;
    const int j     = (n >> 4) & 3;
    const int l15   = n & 15;
    const int rbase = (strip * KSTEPS + ks) * 64 + l15;
#pragma unroll
    for (int qd = 0; qd < 4; ++qd) {
        unsigned short* p = bs + (size_t)(rbase + qd * 16) * 8;
        p[j]     = (unsigned short)(b8[2 * qd] | (b8[2 * qd + 1] << 8));
        p[4 + j] = (qd < 2) ? h0 : h1;
    }
}

// C[256,8192] += X * W^T (bias pre-written), fused 2-bit dequant of W.
// 512 thr = 8 waves = 2m x 4n of 64x64 wave-tiles; BM=128, BN=256.
// Grid (OUT_F/256, M/128, SPLITK). No LDS, no barriers; depth-2 register
// pipeline. Per wave-kstep: 4 A dwordx4 (frag-ordered ws, L1/L2-hot),
// 1 B dwordx4 (repacked stream), 32-weight dequant, 16 MFMA.
template <bool XB, bool BS>
__global__ __launch_bounds__(512, 2) void gemm2bit_kernel(
    const float* __restrict__ xf,     // !XB: fp32 x (frag-gathered)
    const uint4* __restrict__ xb,     // XB: frag-ordered bf16 ws
    const uint4* __restrict__ bs,     // BS: repacked B stream
    const int*   __restrict__ wq,     // !BS: raw packed weights
    const void*  __restrict__ wnorm,  // !BS: raw norms (fp32/fp16 detected)
    float*       __restrict__ out)
{
    const int t    = threadIdx.x;
    const int wave = t >> 6;
    const int lane = t & 63;
    const int l15  = lane & 15;
    const int quad = lane >> 4;
    const int wm   = wave >> 2;            // 0..1
    const int wn   = wave & 3;             // 0..3

    const int gs   = blockIdx.x * 4 + wn;            // global n-strip (64 wide)
    const int m0   = blockIdx.y * 128 + wm * 64;     // wave m base
    const int mb   = blockIdx.y * 8 + wm * 4;        // m-frag base (global)
    const int ks0  = blockIdx.z * NIT;               // first kstep (absolute)

    bool nf32 = false;
    if (!BS) {
        const float cand0 = *(const float*)wnorm;
        nf32 = (cand0 > 1e-5f && cand0 < 0.1f);
    }

    float4v acc[4][4] = {};

    auto loadA = [&](uint4 (&a)[4], int ks) {
        if (XB) {
#pragma unroll
            for (int i = 0; i < 4; ++i)
                a[i] = xb[(size_t)(ks * 16 + mb + i) * 64 + lane];
        } else {
#pragma unroll
            for (int i = 0; i < 4; ++i) {
                const float* p = xf + (size_t)(m0 + i * 16 + l15) * IN_F + ks * 32 + quad * 8;
                float4 v0 = ((const float4*)p)[0], v1 = ((const float4*)p)[1];
                a[i].x = pack_bf16(v0.x, v0.y); a[i].y = pack_bf16(v0.z, v0.w);
                a[i].z = pack_bf16(v1.x, v1.y); a[i].w = pack_bf16(v1.z, v1.w);
            }
        }
    };

    auto loadB = [&](unsigned int (&qb)[4], float (&nm)[4], int ks) {
        if (BS) {
            uint4 v = bs[(size_t)(gs * KSTEPS + ks) * 64 + lane];
            qb[0] = v.x & 0xFFFFu; qb[1] = v.x >> 16;
            qb[2] = v.y & 0xFFFFu; qb[3] = v.y >> 16;
            nm[0] = h2f_bits(v.z & 0xFFFFu); nm[1] = h2f_bits(v.z >> 16);
            nm[2] = h2f_bits(v.w & 0xFFFFu); nm[3] = h2f_bits(v.w >> 16);
        } else {
#pragma unroll
            for (int j = 0; j < 4; ++j) {
                const int n = gs * 64 + j * 16 + l15;
                const int2 q = *(const int2*)((const char*)wq +
                                  (size_t)n * (IN_F / 4) * 4 + (size_t)ks * 32 + quad * 8);
                qb[j] = (unsigned int)((q.x & 0xFF) | ((q.y & 0xFF) << 8));
                const int g = n * (IN_F / 16) + ks * 2 + (quad >> 1);
                nm[j] = nf32 ? ((const float*)wnorm)[g]
                             : h2f_bits(((const unsigned short*)wnorm)[g]);
            }
        }
    };

    auto process = [&](uint4 (&a)[4], unsigned int (&qb)[4], float (&nm)[4]) {
#pragma unroll
        for (int j = 0; j < 4; ++j) {
            const float nC = nm[j];
            const float s  = nC * (2.0f / 3.0f);
            float f[8];
#pragma unroll
            for (int i = 0; i < 4; ++i)
                f[i]     = fmaf((float)((qb[j] >> (2 * i)) & 3), s, -nC);
#pragma unroll
            for (int i = 0; i < 4; ++i)
                f[4 + i] = fmaf((float)((qb[j] >> (8 + 2 * i)) & 3), s, -nC);
            pk8 b;
            b.u.x = pack_bf16(f[0], f[1]); b.u.y = pack_bf16(f[2], f[3]);
            b.u.z = pack_bf16(f[4], f[5]); b.u.w = pack_bf16(f[6], f[7]);
#pragma unroll
            for (int i = 0; i < 4; ++i) {
                pk8 av; av.u = a[i];
                acc[i][j] = __builtin_amdgcn_mfma_f32_16x16x32_bf16(av.s, b.s, acc[i][j], 0, 0, 0);
            }
        }
    };

    // ---- depth-2 register pipeline, no barriers anywhere ----
    uint4 a0[4], a1[4]; unsigned int q0v[4], q1v[4]; float n0v[4], n1v[4];
    loadA(a0, ks0);     loadB(q0v, n0v, ks0);
    loadA(a1, ks0 + 1); loadB(q1v, n1v, ks0 + 1);

    for (int ito = 0; ito < NIT / 2; ++ito) {
        const int it = ks0 + ito * 2;
        process(a0, q0v, n0v);
        if (ito + 1 < NIT / 2) { loadA(a0, it + 2); loadB(q0v, n0v, it + 2); }
        process(a1, q1v, n1v);
        if (ito + 1 < NIT / 2) { loadA(a1, it + 3); loadB(q1v, n1v, it + 3); }
    }

    // ---- epilogue: atomic accumulate split-K partial ----
    // D[row=quad*4+r][col=lane&15] mapping (verified R0-R4)
#pragma unroll
    for (int j = 0; j < 4; ++j) {
        const int col = gs * 64 + j * 16 + l15;
#pragma unroll
        for (int i = 0; i < 4; ++i) {
            const int row0 = m0 + i * 16 + quad * 4;
#pragma unroll
            for (int r = 0; r < 4; ++r)
                atomicAdd(&out[(size_t)(row0 + r) * OUT_F + col], acc[i][j][r]);
        }
    }
}

extern "C" void kernel_launch(void* const* d_in, const int* in_sizes, int n_in,
                              void* d_out, int out_size, void* d_ws, size_t ws_size,
                              hipStream_t stream) {
    const float* x    = (const float*)d_in[0];
    const int*   wq   = (const int*)d_in[1];
    const void*  wn   = (const void*)d_in[2];
    const float* bias = (const float*)d_in[3];
    float*       out  = (float*)d_out;

    const size_t xb_bytes = (size_t)M_ROWS * IN_F * 2;                 // 2 MB
    const size_t bs_bytes = (size_t)NSTRIPS * KSTEPS * 64 * 16;        // 16 MB

    dim3 grid(OUT_F / 256, M_ROWS / 128, SPLITK);  // (32, 2, 4) = 256 blocks

    // out = bias; split-K partials land on top via atomicAdd
    init_out_kernel<<<dim3((M_ROWS * OUT_F / 4) / 256), 256, 0, stream>>>(bias, out);

    if (ws_size >= xb_bytes + bs_bytes) {
        uint4*          xbv = (uint4*)d_ws;
        unsigned short* bsw = (unsigned short*)((char*)d_ws + xb_bytes);
        cvt_x_kernel<<<dim3((M_ROWS * IN_F / 8) / 256), 256, 0, stream>>>(x, xbv);
        repack_w_kernel<<<dim3((OUT_F * KSTEPS) / 256), 256, 0, stream>>>(wq, wn, bsw);
        gemm2bit_kernel<true, true><<<grid, 512, 0, stream>>>(
            nullptr, xbv, (const uint4*)bsw, wq, wn, out);
    } else if (ws_size >= xb_bytes) {
        uint4* xbv = (uint4*)d_ws;
        cvt_x_kernel<<<dim3((M_ROWS * IN_F / 8) / 256), 256, 0, stream>>>(x, xbv);
        gemm2bit_kernel<true, false><<<grid, 512, 0, stream>>>(
            nullptr, xbv, nullptr, wq, wn, out);
    } else {
        gemm2bit_kernel<false, false><<<grid, 512, 0, stream>>>(
            x, nullptr, nullptr, wq, wn, out);
    }
}

// Round 6
// 155.499 us; speedup vs baseline: 1.0997x; 1.0997x over previous
//
#include <hip/hip_runtime.h>
#include <hip/hip_fp16.h>

#define IN_F   4096
#define OUT_F  8192
#define M_ROWS 256

// R6: (1) repack v2 -- LDS-transpose, coalesced reads AND one dwordx4
// coalesced store per record (R5's repack did 8x scattered 2B stores ->
// 50us; this version is BW-bound ~52MB -> ~10us target).
// (2) gemm: SPLITK=8 (512 blocks = 2/CU) + register diet (launch_bounds
// (512,4); B stage = single uint4, norms unpacked in process) to reach
// 4 waves/SIMD (R5 was 2 waves/SIMD: 68 VGPR + ~64 AGPR acc > 128).
#define SPLITK  8
#define KSTEPS  (IN_F / 32)        // 128 ksteps of K=32 total
#define NIT     (KSTEPS / SPLITK)  // 16 ksteps per block
#define NSTRIPS (OUT_F / 64)       // 128 n-strips of 64

typedef __attribute__((ext_vector_type(8))) short  short8;   // 8 bf16
typedef __attribute__((ext_vector_type(4))) float  float4v;  // 4 fp32 acc

union pk8 { uint4 u; short8 s; };
union hbits { __half h; unsigned short u; };

// pack two fp32 into bf16x2 (truncation): [bf16(lo) | bf16(hi)<<16]
__device__ inline unsigned int pack_bf16(float lo, float hi) {
    return __builtin_amdgcn_perm(__float_as_uint(hi), __float_as_uint(lo), 0x07060302u);
}

__device__ inline float h2f_bits(unsigned int b) {
    hbits t; t.u = (unsigned short)b;
    return __half2float(t.h);
}

// x fp32 -> bf16 workspace in FRAGMENT order (R4/R5-verified): for (kstep
// ks, m-frag mf), 64 lanes x 16B; lane (quad,l15) holds
// x[m = mf*16 + l15][k = ks*32 + quad*8 .. +7].
__global__ void cvt_x_kernel(const float* __restrict__ x, uint4* __restrict__ xb) {
    const int tid = blockIdx.x * blockDim.x + threadIdx.x;
    if (tid >= (M_ROWS * IN_F) / 8) return;
    const int lane = tid & 63;
    const int mf   = (tid >> 6) & 15;
    const int ks   = tid >> 10;
    const int m    = mf * 16 + (lane & 15);
    const int k    = ks * 32 + (lane >> 4) * 8;
    const float* p = x + m * IN_F + k;
    float4 v0 = ((const float4*)p)[0], v1 = ((const float4*)p)[1];
    uint4 o;
    o.x = pack_bf16(v0.x, v0.y); o.y = pack_bf16(v0.z, v0.w);
    o.z = pack_bf16(v1.x, v1.y); o.w = pack_bf16(v1.z, v1.w);
    xb[tid] = o;
}

// out[m][n] = bias[n]  (split-K partials atomicAdd on top)
__global__ void init_out_kernel(const float* __restrict__ bias, float* __restrict__ out) {
    int i = blockIdx.x * blockDim.x + threadIdx.x;
    if (i < (M_ROWS * OUT_F) / 4) {
        float4 b = ((const float4*)bias)[i & (OUT_F / 4 - 1)];
        ((float4*)out)[i] = b;
    }
}

// ---- repack v2: LDS-transpose ----
// Block = (strip s: 64 n-rows, kwin w: 32 ksteps = 1024 k). 256 threads.
// Phase A: q bytes (1 useful byte per int32) gathered 4-at-a-time via
//   v_perm into dwords, stored to LDS with chunk^=(row&31) swizzle.
// Phase A2: norms (64 rows x 64 halfs/window) -> LDS, dword p^=(row&31).
// Phase B: each thread emits 8 complete 16B records (coalesced dwordx4).
// Record (s, ks_g, lane): ushort[j] = 2 q-bytes of row j*16+l15 covering
// k = ks_g*32 + quad*8..+7; ushort[4+j] = fp16 norm of that group.
// Bank analysis: all LDS phases conflict-free or 2-way (free).
__global__ __launch_bounds__(256) void repack_w_kernel(
    const int* __restrict__ wq, const void* __restrict__ wnorm,
    uint4* __restrict__ bs) {
    __shared__ unsigned int qlds[64 * 64];   // 16 KB: [row][dword]
    __shared__ unsigned int nlds[64 * 32];   // 8 KB:  [row][dword]

    const int t = threadIdx.x;
    const int s = blockIdx.x;   // strip
    const int w = blockIdx.y;   // kwin

    const float cand0 = *(const float*)wnorm;
    const bool  nf32  = (cand0 > 1e-5f && cand0 < 0.1f);

    // Phase A: window = 256 raw int32 per row (1 byte each)
    {
        const int p    = t & 63;
        const int rsub = t >> 6;
#pragma unroll
        for (int j = 0; j < 16; ++j) {
            const int row  = j * 4 + rsub;
            const int rowg = s * 64 + row;
            int4 d = *(const int4*)(wq + (size_t)rowg * (IN_F / 4) + w * 256 + p * 4);
            // gather LSBs of 4 ints -> 1 dword (window bytes p*4..p*4+3)
            unsigned int t01   = __builtin_amdgcn_perm((unsigned)d.y, (unsigned)d.x, 0x00000400u);
            unsigned int t23   = __builtin_amdgcn_perm((unsigned)d.w, (unsigned)d.z, 0x00000400u);
            unsigned int bytes = __builtin_amdgcn_perm(t23, t01, 0x05040100u);
            const int chunk = (p >> 1) ^ (row & 31);
            qlds[row * 64 + ((chunk << 1) | (p & 1))] = bytes;
        }
    }
    // Phase A2: norms, 64 halfs per row-window (32 dwords)
    {
        const int p    = t & 31;
        const int rsub = t >> 5;
#pragma unroll
        for (int j = 0; j < 8; ++j) {
            const int row  = j * 8 + rsub;
            const int rowg = s * 64 + row;
            unsigned int packed;
            if (nf32) {
                const float2 v = *(const float2*)((const float*)wnorm +
                                   (size_t)rowg * (IN_F / 16) + w * 64 + p * 2);
                hbits a, b; a.h = __float2half(v.x); b.h = __float2half(v.y);
                packed = (unsigned int)a.u | ((unsigned int)b.u << 16);
            } else {
                packed = *(const unsigned int*)((const unsigned short*)wnorm +
                           (size_t)rowg * (IN_F / 16) + w * 64 + p * 2);
            }
            nlds[row * 32 + (p ^ (row & 31))] = packed;
        }
    }
    __syncthreads();

    // Phase B: emit 2048 records, 8 per thread, stores coalesced
    const int base = (s * KSTEPS + w * 32) * 64;
#pragma unroll
    for (int e = 0; e < 8; ++e) {
        const int id   = e * 256 + t;
        const int ks   = id >> 6;      // local kstep 0..31
        const int lane = id & 63;
        const int quad = lane >> 4;
        const int l15  = lane & 15;
        const int q2   = quad >> 1;
        const int hsel = quad & 1;
        unsigned int q16[4], n16[4];
#pragma unroll
        for (int j = 0; j < 4; ++j) {
            const int row = j * 16 + l15;
            const int cs  = ks ^ (row & 31);
            const unsigned int qv = qlds[row * 64 + ((cs << 1) | q2)];
            q16[j] = (qv >> (hsel * 16)) & 0xFFFFu;
            const unsigned int nv = nlds[row * 32 + cs];
            n16[j] = (nv >> (q2 * 16)) & 0xFFFFu;
        }
        uint4 r;
        r.x = q16[0] | (q16[1] << 16);
        r.y = q16[2] | (q16[3] << 16);
        r.z = n16[0] | (n16[1] << 16);
        r.w = n16[2] | (n16[3] << 16);
        bs[base + id] = r;
    }
}

// C[256,8192] += X * W^T (bias pre-written), fused 2-bit dequant of W.
// 512 thr = 8 waves = 2m x 4n of 64x64 wave-tiles; BM=128, BN=256.
// Grid (32, 2, SPLITK=8) = 512 blocks -> 2/CU -> 4 waves/SIMD target.
// No LDS, no barriers; depth-2 register pipeline; B stage = 1 uint4
// (norms unpacked at use to cut live registers).
template <bool XB, bool BS>
__global__ __launch_bounds__(512, 4) void gemm2bit_kernel(
    const float* __restrict__ xf,     // !XB: fp32 x (frag-gathered)
    const uint4* __restrict__ xb,     // XB: frag-ordered bf16 ws
    const uint4* __restrict__ bs,     // BS: repacked B stream
    const int*   __restrict__ wq,     // !BS: raw packed weights
    const void*  __restrict__ wnorm,  // !BS: raw norms (fp32/fp16 detected)
    float*       __restrict__ out)
{
    const int t    = threadIdx.x;
    const int wave = t >> 6;
    const int lane = t & 63;
    const int l15  = lane & 15;
    const int quad = lane >> 4;
    const int wm   = wave >> 2;            // 0..1
    const int wn   = wave & 3;             // 0..3

    const int gs   = blockIdx.x * 4 + wn;            // n-strip (64 wide)
    const int m0   = blockIdx.y * 128 + wm * 64;     // wave m base
    const int mb   = blockIdx.y * 8 + wm * 4;        // m-frag base
    const int ks0  = blockIdx.z * NIT;               // first kstep

    bool nf32 = false;
    if (!BS) {
        const float cand0 = *(const float*)wnorm;
        nf32 = (cand0 > 1e-5f && cand0 < 0.1f);
    }

    float4v acc[4][4] = {};

    auto loadA = [&](uint4 (&a)[4], int ks) {
        if (XB) {
#pragma unroll
            for (int i = 0; i < 4; ++i)
                a[i] = xb[(size_t)(ks * 16 + mb + i) * 64 + lane];
        } else {
#pragma unroll
            for (int i = 0; i < 4; ++i) {
                const float* p = xf + (size_t)(m0 + i * 16 + l15) * IN_F + ks * 32 + quad * 8;
                float4 v0 = ((const float4*)p)[0], v1 = ((const float4*)p)[1];
                a[i].x = pack_bf16(v0.x, v0.y); a[i].y = pack_bf16(v0.z, v0.w);
                a[i].z = pack_bf16(v1.x, v1.y); a[i].w = pack_bf16(v1.z, v1.w);
            }
        }
    };

    auto loadB = [&](uint4& bv, int ks) {
        if (BS) {
            bv = bs[(size_t)(gs * KSTEPS + ks) * 64 + lane];
        } else {
            // fallback: scattered raw loads, assemble the same record
            unsigned int q16[4], n16[4];
#pragma unroll
            for (int j = 0; j < 4; ++j) {
                const int n = gs * 64 + j * 16 + l15;
                const int2 q = *(const int2*)((const char*)wq +
                                  (size_t)n * (IN_F / 4) * 4 + (size_t)ks * 32 + quad * 8);
                q16[j] = (unsigned int)((q.x & 0xFF) | ((q.y & 0xFF) << 8));
                const int g = n * (IN_F / 16) + ks * 2 + (quad >> 1);
                if (nf32) {
                    hbits h; h.h = __float2half(((const float*)wnorm)[g]);
                    n16[j] = h.u;
                } else {
                    n16[j] = ((const unsigned short*)wnorm)[g];
                }
            }
            bv.x = q16[0] | (q16[1] << 16);
            bv.y = q16[2] | (q16[3] << 16);
            bv.z = n16[0] | (n16[1] << 16);
            bv.w = n16[2] | (n16[3] << 16);
        }
    };

    auto process = [&](uint4 (&a)[4], const uint4& bv) {
        const unsigned int qd[2] = { bv.x, bv.y };
        const unsigned int nd[2] = { bv.z, bv.w };
#pragma unroll
        for (int j = 0; j < 4; ++j) {
            const unsigned int qn = (qd[j >> 1] >> ((j & 1) * 16)) & 0xFFFFu;
            const float nC = h2f_bits((nd[j >> 1] >> ((j & 1) * 16)) & 0xFFFFu);
            const float s  = nC * (2.0f / 3.0f);
            float f[8];
#pragma unroll
            for (int i = 0; i < 4; ++i)
                f[i]     = fmaf((float)((qn >> (2 * i)) & 3), s, -nC);
#pragma unroll
            for (int i = 0; i < 4; ++i)
                f[4 + i] = fmaf((float)((qn >> (8 + 2 * i)) & 3), s, -nC);
            pk8 b;
            b.u.x = pack_bf16(f[0], f[1]); b.u.y = pack_bf16(f[2], f[3]);
            b.u.z = pack_bf16(f[4], f[5]); b.u.w = pack_bf16(f[6], f[7]);
#pragma unroll
            for (int i = 0; i < 4; ++i) {
                pk8 av; av.u = a[i];
                acc[i][j] = __builtin_amdgcn_mfma_f32_16x16x32_bf16(av.s, b.s, acc[i][j], 0, 0, 0);
            }
        }
    };

    // ---- depth-2 register pipeline, no barriers anywhere ----
    uint4 a0[4], a1[4]; uint4 b0, b1;
    loadA(a0, ks0);     loadB(b0, ks0);
    loadA(a1, ks0 + 1); loadB(b1, ks0 + 1);

    for (int ito = 0; ito < NIT / 2; ++ito) {
        const int it = ks0 + ito * 2;
        process(a0, b0);
        if (ito + 1 < NIT / 2) { loadA(a0, it + 2); loadB(b0, it + 2); }
        process(a1, b1);
        if (ito + 1 < NIT / 2) { loadA(a1, it + 3); loadB(b1, it + 3); }
    }

    // ---- epilogue: atomic accumulate split-K partial ----
    // D[row=quad*4+r][col=lane&15] mapping (verified R0-R5)
#pragma unroll
    for (int j = 0; j < 4; ++j) {
        const int col = gs * 64 + j * 16 + l15;
#pragma unroll
        for (int i = 0; i < 4; ++i) {
            const int row0 = m0 + i * 16 + quad * 4;
#pragma unroll
            for (int r = 0; r < 4; ++r)
                atomicAdd(&out[(size_t)(row0 + r) * OUT_F + col], acc[i][j][r]);
        }
    }
}

extern "C" void kernel_launch(void* const* d_in, const int* in_sizes, int n_in,
                              void* d_out, int out_size, void* d_ws, size_t ws_size,
                              hipStream_t stream) {
    const float* x    = (const float*)d_in[0];
    const int*   wq   = (const int*)d_in[1];
    const void*  wn   = (const void*)d_in[2];
    const float* bias = (const float*)d_in[3];
    float*       out  = (float*)d_out;

    const size_t xb_bytes = (size_t)M_ROWS * IN_F * 2;            // 2 MB
    const size_t bs_bytes = (size_t)NSTRIPS * KSTEPS * 64 * 16;   // 16 MB

    dim3 grid(OUT_F / 256, M_ROWS / 128, SPLITK);  // (32, 2, 8) = 512 blocks

    // out = bias; split-K partials land on top via atomicAdd
    init_out_kernel<<<dim3((M_ROWS * OUT_F / 4) / 256), 256, 0, stream>>>(bias, out);

    if (ws_size >= xb_bytes + bs_bytes) {
        uint4* xbv = (uint4*)d_ws;
        uint4* bsw = (uint4*)((char*)d_ws + xb_bytes);
        cvt_x_kernel<<<dim3((M_ROWS * IN_F / 8) / 256), 256, 0, stream>>>(x, xbv);
        repack_w_kernel<<<dim3(NSTRIPS, KSTEPS / 32), 256, 0, stream>>>(wq, wn, bsw);
        gemm2bit_kernel<true, true><<<grid, 512, 0, stream>>>(
            nullptr, xbv, bsw, wq, wn, out);
    } else if (ws_size >= xb_bytes) {
        uint4* xbv = (uint4*)d_ws;
        cvt_x_kernel<<<dim3((M_ROWS * IN_F / 8) / 256), 256, 0, stream>>>(x, xbv);
        gemm2bit_kernel<true, false><<<grid, 512, 0, stream>>>(
            nullptr, xbv, nullptr, wq, wn, out);
    } else {
        gemm2bit_kernel<false, false><<<grid, 512, 0, stream>>>(
            x, nullptr, nullptr, wq, wn, out);
    }
}

// Round 7
// 139.327 us; speedup vs baseline: 1.2274x; 1.1161x over previous
//
#include <hip/hip_runtime.h>
#include <hip/hip_fp16.h>

#define IN_F   4096
#define OUT_F  8192
#define M_ROWS 256

// R7: (1) plain-store split-K partials + BW-bound reduce kernel (R6 showed
// atomics cost ~0.57us/MB -> 37us of the 69us gemm). (2) wave n-tile 64->128
// (acc 4x8): halves the redundant A-fragment cache traffic (268->134MB),
// which R5/R6 both rode at an invariant ~8.4 TB/s -- the compute-phase
// ceiling. Repack v2 + cvt + fragment mappings unchanged (verified R4-R6).
#define SPLITK  8
#define KSTEPS  (IN_F / 32)        // 128 ksteps of K=32 total
#define NIT     (KSTEPS / SPLITK)  // 16 ksteps per block
#define NSTRIPS (OUT_F / 64)       // 128 n-strips of 64

typedef __attribute__((ext_vector_type(8))) short  short8;   // 8 bf16
typedef __attribute__((ext_vector_type(4))) float  float4v;  // 4 fp32 acc

union pk8 { uint4 u; short8 s; };
union hbits { __half h; unsigned short u; };

// pack two fp32 into bf16x2 (truncation): [bf16(lo) | bf16(hi)<<16]
__device__ inline unsigned int pack_bf16(float lo, float hi) {
    return __builtin_amdgcn_perm(__float_as_uint(hi), __float_as_uint(lo), 0x07060302u);
}

__device__ inline float h2f_bits(unsigned int b) {
    hbits t; t.u = (unsigned short)b;
    return __half2float(t.h);
}

// x fp32 -> bf16 workspace in FRAGMENT order (R4-R6-verified): for (kstep
// ks, m-frag mf), 64 lanes x 16B; lane (quad,l15) holds
// x[m = mf*16 + l15][k = ks*32 + quad*8 .. +7].
__global__ void cvt_x_kernel(const float* __restrict__ x, uint4* __restrict__ xb) {
    const int tid = blockIdx.x * blockDim.x + threadIdx.x;
    if (tid >= (M_ROWS * IN_F) / 8) return;
    const int lane = tid & 63;
    const int mf   = (tid >> 6) & 15;
    const int ks   = tid >> 10;
    const int m    = mf * 16 + (lane & 15);
    const int k    = ks * 32 + (lane >> 4) * 8;
    const float* p = x + m * IN_F + k;
    float4 v0 = ((const float4*)p)[0], v1 = ((const float4*)p)[1];
    uint4 o;
    o.x = pack_bf16(v0.x, v0.y); o.y = pack_bf16(v0.z, v0.w);
    o.z = pack_bf16(v1.x, v1.y); o.w = pack_bf16(v1.z, v1.w);
    xb[tid] = o;
}

// out[m][n] = bias[n]  (fallback path only: atomics land on top)
__global__ void init_out_kernel(const float* __restrict__ bias, float* __restrict__ out) {
    int i = blockIdx.x * blockDim.x + threadIdx.x;
    if (i < (M_ROWS * OUT_F) / 4) {
        float4 b = ((const float4*)bias)[i & (OUT_F / 4 - 1)];
        ((float4*)out)[i] = b;
    }
}

// out = sum_z P[z] + bias ; P[z] is [M][N] fp32, fully coalesced.
__global__ void reduce_out_kernel(const float4* __restrict__ P,
                                  const float* __restrict__ bias,
                                  float4* __restrict__ out, int splitk) {
    const int i = blockIdx.x * blockDim.x + threadIdx.x;
    if (i >= (M_ROWS * OUT_F) / 4) return;
    float4 s = P[i];
    for (int z = 1; z < splitk; ++z) {
        float4 p = P[(size_t)z * (M_ROWS * OUT_F / 4) + i];
        s.x += p.x; s.y += p.y; s.z += p.z; s.w += p.w;
    }
    float4 b = ((const float4*)bias)[i & (OUT_F / 4 - 1)];
    s.x += b.x; s.y += b.y; s.z += b.z; s.w += b.w;
    out[i] = s;
}

// ---- repack v2: LDS-transpose (verified R6, ~10us) ----
__global__ __launch_bounds__(256) void repack_w_kernel(
    const int* __restrict__ wq, const void* __restrict__ wnorm,
    uint4* __restrict__ bs) {
    __shared__ unsigned int qlds[64 * 64];   // 16 KB: [row][dword]
    __shared__ unsigned int nlds[64 * 32];   // 8 KB:  [row][dword]

    const int t = threadIdx.x;
    const int s = blockIdx.x;   // strip
    const int w = blockIdx.y;   // kwin

    const float cand0 = *(const float*)wnorm;
    const bool  nf32  = (cand0 > 1e-5f && cand0 < 0.1f);

    {
        const int p    = t & 63;
        const int rsub = t >> 6;
#pragma unroll
        for (int j = 0; j < 16; ++j) {
            const int row  = j * 4 + rsub;
            const int rowg = s * 64 + row;
            int4 d = *(const int4*)(wq + (size_t)rowg * (IN_F / 4) + w * 256 + p * 4);
            unsigned int t01   = __builtin_amdgcn_perm((unsigned)d.y, (unsigned)d.x, 0x00000400u);
            unsigned int t23   = __builtin_amdgcn_perm((unsigned)d.w, (unsigned)d.z, 0x00000400u);
            unsigned int bytes = __builtin_amdgcn_perm(t23, t01, 0x05040100u);
            const int chunk = (p >> 1) ^ (row & 31);
            qlds[row * 64 + ((chunk << 1) | (p & 1))] = bytes;
        }
    }
    {
        const int p    = t & 31;
        const int rsub = t >> 5;
#pragma unroll
        for (int j = 0; j < 8; ++j) {
            const int row  = j * 8 + rsub;
            const int rowg = s * 64 + row;
            unsigned int packed;
            if (nf32) {
                const float2 v = *(const float2*)((const float*)wnorm +
                                   (size_t)rowg * (IN_F / 16) + w * 64 + p * 2);
                hbits a, b; a.h = __float2half(v.x); b.h = __float2half(v.y);
                packed = (unsigned int)a.u | ((unsigned int)b.u << 16);
            } else {
                packed = *(const unsigned int*)((const unsigned short*)wnorm +
                           (size_t)rowg * (IN_F / 16) + w * 64 + p * 2);
            }
            nlds[row * 32 + (p ^ (row & 31))] = packed;
        }
    }
    __syncthreads();

    const int base = (s * KSTEPS + w * 32) * 64;
#pragma unroll
    for (int e = 0; e < 8; ++e) {
        const int id   = e * 256 + t;
        const int ks   = id >> 6;
        const int lane = id & 63;
        const int quad = lane >> 4;
        const int l15  = lane & 15;
        const int q2   = quad >> 1;
        const int hsel = quad & 1;
        unsigned int q16[4], n16[4];
#pragma unroll
        for (int j = 0; j < 4; ++j) {
            const int row = j * 16 + l15;
            const int cs  = ks ^ (row & 31);
            const unsigned int qv = qlds[row * 64 + ((cs << 1) | q2)];
            q16[j] = (qv >> (hsel * 16)) & 0xFFFFu;
            const unsigned int nv = nlds[row * 32 + cs];
            n16[j] = (nv >> (q2 * 16)) & 0xFFFFu;
        }
        uint4 r;
        r.x = q16[0] | (q16[1] << 16);
        r.y = q16[2] | (q16[3] << 16);
        r.z = n16[0] | (n16[1] << 16);
        r.w = n16[2] | (n16[3] << 16);
        bs[base + id] = r;
    }
}

// C partial[z][256,8192] = X * W^T over this block's K range.
// 512 thr = 8 waves = 2m x 4n of 64m x 128n wave-tiles; BM=128, BN=512.
// Grid (16, 2, SPLITK=8) = 256 blocks. No LDS, no barriers; depth-2
// register pipeline; per wave-kstep: 4 A dwordx4 + 2 B dwordx4 (two
// adjacent n-strip records), 64-weight dequant, 32 MFMA.
template <bool XB, bool BS, bool PW>
__global__ __launch_bounds__(512, 2) void gemm2bit_kernel(
    const float* __restrict__ xf,     // !XB: fp32 x (frag-gathered)
    const uint4* __restrict__ xb,     // XB: frag-ordered bf16 ws
    const uint4* __restrict__ bs,     // BS: repacked B stream
    const int*   __restrict__ wq,     // !BS: raw packed weights
    const void*  __restrict__ wnorm,  // !BS: raw norms (fp32/fp16 detected)
    float*       __restrict__ out)    // PW: partial base; !PW: out (atomics)
{
    const int t    = threadIdx.x;
    const int wave = t >> 6;
    const int lane = t & 63;
    const int l15  = lane & 15;
    const int quad = lane >> 4;
    const int wm   = wave >> 2;            // 0..1
    const int wn   = wave & 3;             // 0..3

    const int s0   = blockIdx.x * 8 + wn * 2;        // first of 2 n-strips
    const int m0   = blockIdx.y * 128 + wm * 64;     // wave m base
    const int mb   = blockIdx.y * 8 + wm * 4;        // m-frag base
    const int ks0  = blockIdx.z * NIT;               // first kstep

    bool nf32 = false;
    if (!BS) {
        const float cand0 = *(const float*)wnorm;
        nf32 = (cand0 > 1e-5f && cand0 < 0.1f);
    }

    float4v acc[4][8] = {};

    auto loadA = [&](uint4 (&a)[4], int ks) {
        if (XB) {
#pragma unroll
            for (int i = 0; i < 4; ++i)
                a[i] = xb[(size_t)(ks * 16 + mb + i) * 64 + lane];
        } else {
#pragma unroll
            for (int i = 0; i < 4; ++i) {
                const float* p = xf + (size_t)(m0 + i * 16 + l15) * IN_F + ks * 32 + quad * 8;
                float4 v0 = ((const float4*)p)[0], v1 = ((const float4*)p)[1];
                a[i].x = pack_bf16(v0.x, v0.y); a[i].y = pack_bf16(v0.z, v0.w);
                a[i].z = pack_bf16(v1.x, v1.y); a[i].w = pack_bf16(v1.z, v1.w);
            }
        }
    };

    auto loadB1 = [&](uint4& bv, int strip, int ks) {
        if (BS) {
            bv = bs[(size_t)(strip * KSTEPS + ks) * 64 + lane];
        } else {
            unsigned int q16[4], n16[4];
#pragma unroll
            for (int j = 0; j < 4; ++j) {
                const int n = strip * 64 + j * 16 + l15;
                const int2 q = *(const int2*)((const char*)wq +
                                  (size_t)n * (IN_F / 4) * 4 + (size_t)ks * 32 + quad * 8);
                q16[j] = (unsigned int)((q.x & 0xFF) | ((q.y & 0xFF) << 8));
                const int g = n * (IN_F / 16) + ks * 2 + (quad >> 1);
                if (nf32) {
                    hbits h; h.h = __float2half(((const float*)wnorm)[g]);
                    n16[j] = h.u;
                } else {
                    n16[j] = ((const unsigned short*)wnorm)[g];
                }
            }
            bv.x = q16[0] | (q16[1] << 16);
            bv.y = q16[2] | (q16[3] << 16);
            bv.z = n16[0] | (n16[1] << 16);
            bv.w = n16[2] | (n16[3] << 16);
        }
    };

    auto procRec = [&](uint4 (&a)[4], const uint4& bv, int jb) {
        const unsigned int qd[2] = { bv.x, bv.y };
        const unsigned int nd[2] = { bv.z, bv.w };
#pragma unroll
        for (int j = 0; j < 4; ++j) {
            const unsigned int qn = (qd[j >> 1] >> ((j & 1) * 16)) & 0xFFFFu;
            const float nC = h2f_bits((nd[j >> 1] >> ((j & 1) * 16)) & 0xFFFFu);
            const float s  = nC * (2.0f / 3.0f);
            float f[8];
#pragma unroll
            for (int i = 0; i < 4; ++i)
                f[i]     = fmaf((float)((qn >> (2 * i)) & 3), s, -nC);
#pragma unroll
            for (int i = 0; i < 4; ++i)
                f[4 + i] = fmaf((float)((qn >> (8 + 2 * i)) & 3), s, -nC);
            pk8 b;
            b.u.x = pack_bf16(f[0], f[1]); b.u.y = pack_bf16(f[2], f[3]);
            b.u.z = pack_bf16(f[4], f[5]); b.u.w = pack_bf16(f[6], f[7]);
#pragma unroll
            for (int i = 0; i < 4; ++i) {
                pk8 av; av.u = a[i];
                acc[i][jb + j] = __builtin_amdgcn_mfma_f32_16x16x32_bf16(av.s, b.s, acc[i][jb + j], 0, 0, 0);
            }
        }
    };

    // ---- depth-2 register pipeline, no barriers anywhere ----
    uint4 a0[4], a1[4], b0[2], b1[2];
    loadA(a0, ks0);     loadB1(b0[0], s0, ks0);     loadB1(b0[1], s0 + 1, ks0);
    loadA(a1, ks0 + 1); loadB1(b1[0], s0, ks0 + 1); loadB1(b1[1], s0 + 1, ks0 + 1);

    for (int it = 0; it < NIT; it += 2) {
        procRec(a0, b0[0], 0); procRec(a0, b0[1], 4);
        if (it + 2 < NIT) {
            const int ks = ks0 + it + 2;
            loadA(a0, ks); loadB1(b0[0], s0, ks); loadB1(b0[1], s0 + 1, ks);
        }
        procRec(a1, b1[0], 0); procRec(a1, b1[1], 4);
        if (it + 3 < NIT) {
            const int ks = ks0 + it + 3;
            loadA(a1, ks); loadB1(b1[0], s0, ks); loadB1(b1[1], s0 + 1, ks);
        }
    }

    // ---- epilogue: D[row=quad*4+r][col=lane&15] mapping (verified R0-R6) ----
    if (PW) {
        float* P = out + (size_t)blockIdx.z * (M_ROWS * OUT_F);
#pragma unroll
        for (int j = 0; j < 8; ++j) {
            const int col = s0 * 64 + (j >> 2) * 64 + (j & 3) * 16 + l15;
#pragma unroll
            for (int i = 0; i < 4; ++i) {
                const int row0 = m0 + i * 16 + quad * 4;
#pragma unroll
                for (int r = 0; r < 4; ++r)
                    P[(size_t)(row0 + r) * OUT_F + col] = acc[i][j][r];
            }
        }
    } else {
#pragma unroll
        for (int j = 0; j < 8; ++j) {
            const int col = s0 * 64 + (j >> 2) * 64 + (j & 3) * 16 + l15;
#pragma unroll
            for (int i = 0; i < 4; ++i) {
                const int row0 = m0 + i * 16 + quad * 4;
#pragma unroll
                for (int r = 0; r < 4; ++r)
                    atomicAdd(&out[(size_t)(row0 + r) * OUT_F + col], acc[i][j][r]);
            }
        }
    }
}

extern "C" void kernel_launch(void* const* d_in, const int* in_sizes, int n_in,
                              void* d_out, int out_size, void* d_ws, size_t ws_size,
                              hipStream_t stream) {
    const float* x    = (const float*)d_in[0];
    const int*   wq   = (const int*)d_in[1];
    const void*  wn   = (const void*)d_in[2];
    const float* bias = (const float*)d_in[3];
    float*       out  = (float*)d_out;

    const size_t xb_bytes = (size_t)M_ROWS * IN_F * 2;            // 2 MB
    const size_t bs_bytes = (size_t)NSTRIPS * KSTEPS * 64 * 16;   // 16 MB
    const size_t pw_bytes = (size_t)SPLITK * M_ROWS * OUT_F * 4;  // 64 MB

    dim3 grid(OUT_F / 512, M_ROWS / 128, SPLITK);  // (16, 2, 8) = 256 blocks

    if (ws_size >= xb_bytes + bs_bytes + pw_bytes) {
        // full path: frag-ordered A + repacked B + partial stores + reduce
        uint4* xbv = (uint4*)d_ws;
        uint4* bsw = (uint4*)((char*)d_ws + xb_bytes);
        float* pw  = (float*)((char*)d_ws + xb_bytes + bs_bytes);
        cvt_x_kernel<<<dim3((M_ROWS * IN_F / 8) / 256), 256, 0, stream>>>(x, xbv);
        repack_w_kernel<<<dim3(NSTRIPS, KSTEPS / 32), 256, 0, stream>>>(wq, wn, bsw);
        gemm2bit_kernel<true, true, true><<<grid, 512, 0, stream>>>(
            nullptr, xbv, bsw, wq, wn, pw);
        reduce_out_kernel<<<dim3((M_ROWS * OUT_F / 4) / 256), 256, 0, stream>>>(
            (const float4*)pw, bias, (float4*)out, SPLITK);
    } else if (ws_size >= xb_bytes + bs_bytes) {
        uint4* xbv = (uint4*)d_ws;
        uint4* bsw = (uint4*)((char*)d_ws + xb_bytes);
        init_out_kernel<<<dim3((M_ROWS * OUT_F / 4) / 256), 256, 0, stream>>>(bias, out);
        cvt_x_kernel<<<dim3((M_ROWS * IN_F / 8) / 256), 256, 0, stream>>>(x, xbv);
        repack_w_kernel<<<dim3(NSTRIPS, KSTEPS / 32), 256, 0, stream>>>(wq, wn, bsw);
        gemm2bit_kernel<true, true, false><<<grid, 512, 0, stream>>>(
            nullptr, xbv, bsw, wq, wn, out);
    } else if (ws_size >= xb_bytes) {
        uint4* xbv = (uint4*)d_ws;
        init_out_kernel<<<dim3((M_ROWS * OUT_F / 4) / 256), 256, 0, stream>>>(bias, out);
        cvt_x_kernel<<<dim3((M_ROWS * IN_F / 8) / 256), 256, 0, stream>>>(x, xbv);
        gemm2bit_kernel<true, false, false><<<grid, 512, 0, stream>>>(
            nullptr, xbv, nullptr, wq, wn, out);
    } else {
        init_out_kernel<<<dim3((M_ROWS * OUT_F / 4) / 256), 256, 0, stream>>>(bias, out);
        gemm2bit_kernel<false, false, false><<<grid, 512, 0, stream>>>(
            x, nullptr, nullptr, wq, wn, out);
    }
}

// Round 8
// 137.897 us; speedup vs baseline: 1.2401x; 1.0104x over previous
//
#include <hip/hip_runtime.h>
#include <hip/hip_fp16.h>

#define IN_F   4096
#define OUT_F  8192
#define M_ROWS 256

// R8: (1) B-stream prefetch depth 4 (A depth 2): at 2 waves/SIMD (200 VGPR)
// the depth-2 pipeline gave ~350cy cover vs ~900cy HBM latency on the cold
// B stream -- R7's gemm was ~half latency exposure. Full unroll keeps all
// pipeline-buffer indices static (no scratch). (2) cvt_x fused into the
// repack launch (one fewer graph node). (3) reduce unrolled at compile time.
// Harness note: the 41us fillBufferAligned (268MB ws poison) is inside the
// measured graph every round and is not controllable from kernel code.
#define SPLITK  8
#define KSTEPS  (IN_F / 32)        // 128 ksteps of K=32 total
#define NIT     (KSTEPS / SPLITK)  // 16 ksteps per block
#define NSTRIPS (OUT_F / 64)       // 128 n-strips of 64

typedef __attribute__((ext_vector_type(8))) short  short8;   // 8 bf16
typedef __attribute__((ext_vector_type(4))) float  float4v;  // 4 fp32 acc

union pk8 { uint4 u; short8 s; };
union hbits { __half h; unsigned short u; };

// pack two fp32 into bf16x2 (truncation): [bf16(lo) | bf16(hi)<<16]
__device__ inline unsigned int pack_bf16(float lo, float hi) {
    return __builtin_amdgcn_perm(__float_as_uint(hi), __float_as_uint(lo), 0x07060302u);
}

__device__ inline float h2f_bits(unsigned int b) {
    hbits t; t.u = (unsigned short)b;
    return __half2float(t.h);
}

// out[m][n] = bias[n]  (fallback path only: atomics land on top)
__global__ void init_out_kernel(const float* __restrict__ bias, float* __restrict__ out) {
    int i = blockIdx.x * blockDim.x + threadIdx.x;
    if (i < (M_ROWS * OUT_F) / 4) {
        float4 b = ((const float4*)bias)[i & (OUT_F / 4 - 1)];
        ((float4*)out)[i] = b;
    }
}

// standalone cvt (fallback paths)
__global__ void cvt_x_kernel(const float* __restrict__ x, uint4* __restrict__ xb) {
    const int tid = blockIdx.x * blockDim.x + threadIdx.x;
    if (tid >= (M_ROWS * IN_F) / 8) return;
    const int lane = tid & 63;
    const int mf   = (tid >> 6) & 15;
    const int ks   = tid >> 10;
    const int m    = mf * 16 + (lane & 15);
    const int k    = ks * 32 + (lane >> 4) * 8;
    const float* p = x + m * IN_F + k;
    float4 v0 = ((const float4*)p)[0], v1 = ((const float4*)p)[1];
    uint4 o;
    o.x = pack_bf16(v0.x, v0.y); o.y = pack_bf16(v0.z, v0.w);
    o.z = pack_bf16(v1.x, v1.y); o.w = pack_bf16(v1.z, v1.w);
    xb[tid] = o;
}

// out = sum_z P[z] + bias ; P[z] is [M][N] fp32, fully coalesced.
__global__ void reduce_out_kernel(const float4* __restrict__ P,
                                  const float* __restrict__ bias,
                                  float4* __restrict__ out) {
    const int i = blockIdx.x * blockDim.x + threadIdx.x;
    if (i >= (M_ROWS * OUT_F) / 4) return;
    float4 s = P[i];
#pragma unroll
    for (int z = 1; z < SPLITK; ++z) {
        float4 p = P[(size_t)z * (M_ROWS * OUT_F / 4) + i];
        s.x += p.x; s.y += p.y; s.z += p.z; s.w += p.w;
    }
    float4 b = ((const float4*)bias)[i & (OUT_F / 4 - 1)];
    s.x += b.x; s.y += b.y; s.z += b.z; s.w += b.w;
    out[i] = s;
}

// ---- repack v2 (LDS-transpose, verified R6/R7) + fused cvt_x ----
// grid (NSTRIPS, 5): w<4 -> repack window w of strip s; w==4 -> cvt_x
// slice (128 blocks x 256 thr x 4 chunks = full x).
// x fp32 -> bf16 ws in FRAGMENT order (R4-R7-verified): lane (quad,l15) of
// record (ks, mf) holds x[mf*16+l15][ks*32 + quad*8 .. +7].
__global__ __launch_bounds__(256) void prep_kernel(
    const int* __restrict__ wq, const void* __restrict__ wnorm,
    uint4* __restrict__ bs, const float* __restrict__ x,
    uint4* __restrict__ xb) {
    __shared__ unsigned int qlds[64 * 64];   // 16 KB: [row][dword]
    __shared__ unsigned int nlds[64 * 32];   // 8 KB:  [row][dword]

    const int t = threadIdx.x;
    const int s = blockIdx.x;   // strip (or cvt slice)
    const int w = blockIdx.y;   // kwin | 4 = cvt

    if (w == 4) {
        // ---- cvt_x part ----
#pragma unroll
        for (int e = 0; e < 4; ++e) {
            const int tid = e * (NSTRIPS * 256) + s * 256 + t;
            const int lane = tid & 63;
            const int mf   = (tid >> 6) & 15;
            const int ks   = tid >> 10;
            const int m    = mf * 16 + (lane & 15);
            const int k    = ks * 32 + (lane >> 4) * 8;
            const float* p = x + (size_t)m * IN_F + k;
            float4 v0 = ((const float4*)p)[0], v1 = ((const float4*)p)[1];
            uint4 o;
            o.x = pack_bf16(v0.x, v0.y); o.y = pack_bf16(v0.z, v0.w);
            o.z = pack_bf16(v1.x, v1.y); o.w = pack_bf16(v1.z, v1.w);
            xb[tid] = o;
        }
        return;
    }

    const float cand0 = *(const float*)wnorm;
    const bool  nf32  = (cand0 > 1e-5f && cand0 < 0.1f);

    {
        const int p    = t & 63;
        const int rsub = t >> 6;
#pragma unroll
        for (int j = 0; j < 16; ++j) {
            const int row  = j * 4 + rsub;
            const int rowg = s * 64 + row;
            int4 d = *(const int4*)(wq + (size_t)rowg * (IN_F / 4) + w * 256 + p * 4);
            unsigned int t01   = __builtin_amdgcn_perm((unsigned)d.y, (unsigned)d.x, 0x00000400u);
            unsigned int t23   = __builtin_amdgcn_perm((unsigned)d.w, (unsigned)d.z, 0x00000400u);
            unsigned int bytes = __builtin_amdgcn_perm(t23, t01, 0x05040100u);
            const int chunk = (p >> 1) ^ (row & 31);
            qlds[row * 64 + ((chunk << 1) | (p & 1))] = bytes;
        }
    }
    {
        const int p    = t & 31;
        const int rsub = t >> 5;
#pragma unroll
        for (int j = 0; j < 8; ++j) {
            const int row  = j * 8 + rsub;
            const int rowg = s * 64 + row;
            unsigned int packed;
            if (nf32) {
                const float2 v = *(const float2*)((const float*)wnorm +
                                   (size_t)rowg * (IN_F / 16) + w * 64 + p * 2);
                hbits a, b; a.h = __float2half(v.x); b.h = __float2half(v.y);
                packed = (unsigned int)a.u | ((unsigned int)b.u << 16);
            } else {
                packed = *(const unsigned int*)((const unsigned short*)wnorm +
                           (size_t)rowg * (IN_F / 16) + w * 64 + p * 2);
            }
            nlds[row * 32 + (p ^ (row & 31))] = packed;
        }
    }
    __syncthreads();

    const int base = (s * KSTEPS + w * 32) * 64;
#pragma unroll
    for (int e = 0; e < 8; ++e) {
        const int id   = e * 256 + t;
        const int ks   = id >> 6;
        const int lane = id & 63;
        const int quad = lane >> 4;
        const int l15  = lane & 15;
        const int q2   = quad >> 1;
        const int hsel = quad & 1;
        unsigned int q16[4], n16[4];
#pragma unroll
        for (int j = 0; j < 4; ++j) {
            const int row = j * 16 + l15;
            const int cs  = ks ^ (row & 31);
            const unsigned int qv = qlds[row * 64 + ((cs << 1) | q2)];
            q16[j] = (qv >> (hsel * 16)) & 0xFFFFu;
            const unsigned int nv = nlds[row * 32 + cs];
            n16[j] = (nv >> (q2 * 16)) & 0xFFFFu;
        }
        uint4 r;
        r.x = q16[0] | (q16[1] << 16);
        r.y = q16[2] | (q16[3] << 16);
        r.z = n16[0] | (n16[1] << 16);
        r.w = n16[2] | (n16[3] << 16);
        bs[base + id] = r;
    }
}

// C partial[z][256,8192] = X * W^T over this block's K range.
// 512 thr = 8 waves = 2m x 4n of 64m x 128n wave-tiles; BM=128, BN=512.
// Grid (16, 2, SPLITK=8) = 256 blocks. No LDS, no barriers. A: depth-2
// (L1/L2-hot); B: depth-4 (cold HBM stream, ~3 process-phases of cover).
template <bool XB, bool BS, bool PW>
__global__ __launch_bounds__(512, 2) void gemm2bit_kernel(
    const float* __restrict__ xf,     // !XB: fp32 x (frag-gathered)
    const uint4* __restrict__ xb,     // XB: frag-ordered bf16 ws
    const uint4* __restrict__ bs,     // BS: repacked B stream
    const int*   __restrict__ wq,     // !BS: raw packed weights
    const void*  __restrict__ wnorm,  // !BS: raw norms (fp32/fp16 detected)
    float*       __restrict__ out)    // PW: partial base; !PW: out (atomics)
{
    const int t    = threadIdx.x;
    const int wave = t >> 6;
    const int lane = t & 63;
    const int l15  = lane & 15;
    const int quad = lane >> 4;
    const int wm   = wave >> 2;            // 0..1
    const int wn   = wave & 3;             // 0..3

    const int s0   = blockIdx.x * 8 + wn * 2;        // first of 2 n-strips
    const int m0   = blockIdx.y * 128 + wm * 64;     // wave m base
    const int mb   = blockIdx.y * 8 + wm * 4;        // m-frag base
    const int ks0  = blockIdx.z * NIT;               // first kstep

    bool nf32 = false;
    if (!BS) {
        const float cand0 = *(const float*)wnorm;
        nf32 = (cand0 > 1e-5f && cand0 < 0.1f);
    }

    float4v acc[4][8] = {};

    auto loadA = [&](uint4 (&a)[4], int ks) {
        if (XB) {
#pragma unroll
            for (int i = 0; i < 4; ++i)
                a[i] = xb[(size_t)(ks * 16 + mb + i) * 64 + lane];
        } else {
#pragma unroll
            for (int i = 0; i < 4; ++i) {
                const float* p = xf + (size_t)(m0 + i * 16 + l15) * IN_F + ks * 32 + quad * 8;
                float4 v0 = ((const float4*)p)[0], v1 = ((const float4*)p)[1];
                a[i].x = pack_bf16(v0.x, v0.y); a[i].y = pack_bf16(v0.z, v0.w);
                a[i].z = pack_bf16(v1.x, v1.y); a[i].w = pack_bf16(v1.z, v1.w);
            }
        }
    };

    auto loadB1 = [&](uint4& bv, int strip, int ks) {
        if (BS) {
            bv = bs[(size_t)(strip * KSTEPS + ks) * 64 + lane];
        } else {
            unsigned int q16[4], n16[4];
#pragma unroll
            for (int j = 0; j < 4; ++j) {
                const int n = strip * 64 + j * 16 + l15;
                const int2 q = *(const int2*)((const char*)wq +
                                  (size_t)n * (IN_F / 4) * 4 + (size_t)ks * 32 + quad * 8);
                q16[j] = (unsigned int)((q.x & 0xFF) | ((q.y & 0xFF) << 8));
                const int g = n * (IN_F / 16) + ks * 2 + (quad >> 1);
                if (nf32) {
                    hbits h; h.h = __float2half(((const float*)wnorm)[g]);
                    n16[j] = h.u;
                } else {
                    n16[j] = ((const unsigned short*)wnorm)[g];
                }
            }
            bv.x = q16[0] | (q16[1] << 16);
            bv.y = q16[2] | (q16[3] << 16);
            bv.z = n16[0] | (n16[1] << 16);
            bv.w = n16[2] | (n16[3] << 16);
        }
    };

    auto procRec = [&](uint4 (&a)[4], const uint4& bv, int jb) {
        const unsigned int qd[2] = { bv.x, bv.y };
        const unsigned int nd[2] = { bv.z, bv.w };
#pragma unroll
        for (int j = 0; j < 4; ++j) {
            const unsigned int qn = (qd[j >> 1] >> ((j & 1) * 16)) & 0xFFFFu;
            const float nC = h2f_bits((nd[j >> 1] >> ((j & 1) * 16)) & 0xFFFFu);
            const float s  = nC * (2.0f / 3.0f);
            float f[8];
#pragma unroll
            for (int i = 0; i < 4; ++i)
                f[i]     = fmaf((float)((qn >> (2 * i)) & 3), s, -nC);
#pragma unroll
            for (int i = 0; i < 4; ++i)
                f[4 + i] = fmaf((float)((qn >> (8 + 2 * i)) & 3), s, -nC);
            pk8 b;
            b.u.x = pack_bf16(f[0], f[1]); b.u.y = pack_bf16(f[2], f[3]);
            b.u.z = pack_bf16(f[4], f[5]); b.u.w = pack_bf16(f[6], f[7]);
#pragma unroll
            for (int i = 0; i < 4; ++i) {
                pk8 av; av.u = a[i];
                acc[i][jb + j] = __builtin_amdgcn_mfma_f32_16x16x32_bf16(av.s, b.s, acc[i][jb + j], 0, 0, 0);
            }
        }
    };

    // ---- pipeline: A depth-2, B depth-4; fully unrolled (static indices) ----
    uint4 a0[4], a1[4], bb[4][2];
    loadA(a0, ks0); loadA(a1, ks0 + 1);
#pragma unroll
    for (int d = 0; d < 4; ++d) {
        loadB1(bb[d][0], s0, ks0 + d);
        loadB1(bb[d][1], s0 + 1, ks0 + d);
    }

#pragma unroll
    for (int it = 0; it < NIT; it += 2) {
        procRec(a0, bb[it & 3][0], 0); procRec(a0, bb[it & 3][1], 4);
        if (it + 2 < NIT) loadA(a0, ks0 + it + 2);
        if (it + 4 < NIT) {
            loadB1(bb[it & 3][0], s0, ks0 + it + 4);
            loadB1(bb[it & 3][1], s0 + 1, ks0 + it + 4);
        }
        procRec(a1, bb[(it + 1) & 3][0], 0); procRec(a1, bb[(it + 1) & 3][1], 4);
        if (it + 3 < NIT) loadA(a1, ks0 + it + 3);
        if (it + 5 < NIT) {
            loadB1(bb[(it + 1) & 3][0], s0, ks0 + it + 5);
            loadB1(bb[(it + 1) & 3][1], s0 + 1, ks0 + it + 5);
        }
    }

    // ---- epilogue: D[row=quad*4+r][col=lane&15] mapping (verified R0-R7) ----
    if (PW) {
        float* P = out + (size_t)blockIdx.z * (M_ROWS * OUT_F);
#pragma unroll
        for (int j = 0; j < 8; ++j) {
            const int col = s0 * 64 + (j >> 2) * 64 + (j & 3) * 16 + l15;
#pragma unroll
            for (int i = 0; i < 4; ++i) {
                const int row0 = m0 + i * 16 + quad * 4;
#pragma unroll
                for (int r = 0; r < 4; ++r)
                    P[(size_t)(row0 + r) * OUT_F + col] = acc[i][j][r];
            }
        }
    } else {
#pragma unroll
        for (int j = 0; j < 8; ++j) {
            const int col = s0 * 64 + (j >> 2) * 64 + (j & 3) * 16 + l15;
#pragma unroll
            for (int i = 0; i < 4; ++i) {
                const int row0 = m0 + i * 16 + quad * 4;
#pragma unroll
                for (int r = 0; r < 4; ++r)
                    atomicAdd(&out[(size_t)(row0 + r) * OUT_F + col], acc[i][j][r]);
            }
        }
    }
}

extern "C" void kernel_launch(void* const* d_in, const int* in_sizes, int n_in,
                              void* d_out, int out_size, void* d_ws, size_t ws_size,
                              hipStream_t stream) {
    const float* x    = (const float*)d_in[0];
    const int*   wq   = (const int*)d_in[1];
    const void*  wn   = (const void*)d_in[2];
    const float* bias = (const float*)d_in[3];
    float*       out  = (float*)d_out;

    const size_t xb_bytes = (size_t)M_ROWS * IN_F * 2;            // 2 MB
    const size_t bs_bytes = (size_t)NSTRIPS * KSTEPS * 64 * 16;   // 16 MB
    const size_t pw_bytes = (size_t)SPLITK * M_ROWS * OUT_F * 4;  // 64 MB

    dim3 grid(OUT_F / 512, M_ROWS / 128, SPLITK);  // (16, 2, 8) = 256 blocks

    if (ws_size >= xb_bytes + bs_bytes + pw_bytes) {
        // full path: fused prep (cvt + repack) + gemm partials + reduce
        uint4* xbv = (uint4*)d_ws;
        uint4* bsw = (uint4*)((char*)d_ws + xb_bytes);
        float* pw  = (float*)((char*)d_ws + xb_bytes + bs_bytes);
        prep_kernel<<<dim3(NSTRIPS, 5), 256, 0, stream>>>(wq, wn, bsw, x, xbv);
        gemm2bit_kernel<true, true, true><<<grid, 512, 0, stream>>>(
            nullptr, xbv, bsw, wq, wn, pw);
        reduce_out_kernel<<<dim3((M_ROWS * OUT_F / 4) / 256), 256, 0, stream>>>(
            (const float4*)pw, bias, (float4*)out);
    } else if (ws_size >= xb_bytes + bs_bytes) {
        uint4* xbv = (uint4*)d_ws;
        uint4* bsw = (uint4*)((char*)d_ws + xb_bytes);
        init_out_kernel<<<dim3((M_ROWS * OUT_F / 4) / 256), 256, 0, stream>>>(bias, out);
        prep_kernel<<<dim3(NSTRIPS, 5), 256, 0, stream>>>(wq, wn, bsw, x, xbv);
        gemm2bit_kernel<true, true, false><<<grid, 512, 0, stream>>>(
            nullptr, xbv, bsw, wq, wn, out);
    } else if (ws_size >= xb_bytes) {
        uint4* xbv = (uint4*)d_ws;
        init_out_kernel<<<dim3((M_ROWS * OUT_F / 4) / 256), 256, 0, stream>>>(bias, out);
        cvt_x_kernel<<<dim3((M_ROWS * IN_F / 8) / 256), 256, 0, stream>>>(x, xbv);
        gemm2bit_kernel<true, false, false><<<grid, 512, 0, stream>>>(
            nullptr, xbv, nullptr, wq, wn, out);
    } else {
        init_out_kernel<<<dim3((M_ROWS * OUT_F / 4) / 256), 256, 0, stream>>>(bias, out);
        gemm2bit_kernel<false, false, false><<<grid, 512, 0, stream>>>(
            x, nullptr, nullptr, wq, wn, out);
    }
}